// Round 4
// baseline (111.340 us; speedup 1.0000x reference)
//
#include <hip/hip_runtime.h>
#include <cstddef>

#define Bq 16
#define TEq 128
#define TDq 128
#define Hq 256

#define kC2  2.8853900817779268f  /* 2*log2(e) */
#define kL2E 1.4426950408889634f

static __device__ __forceinline__ float fast_rcp(float x) {
#if __has_builtin(__builtin_amdgcn_rcpf)
    return __builtin_amdgcn_rcpf(x);
#else
    return 1.0f / x;
#endif
}

static __device__ __forceinline__ float fast_exp2(float x) {
#if __has_builtin(__builtin_amdgcn_exp2f)
    return __builtin_amdgcn_exp2f(x);
#else
    return exp2f(x);
#endif
}

// ---------------------------------------------------------------------------
// K1: orthogonalize. Exclusive cumsum over TE split into 8 chunks of 16 per
// (b,h); chunk partials exchanged via LDS; x held in registers (loaded once).
// ---------------------------------------------------------------------------
__global__ __launch_bounds__(256) void k_ortho(const float* __restrict__ enc,
                                               float* __restrict__ out) {
    const int b = blockIdx.y;
    const int hg = blockIdx.x;            // 0..7
    const int tid = threadIdx.x;
    const int hl = tid & 31;
    const int ck = tid >> 5;              // chunk 0..7 (16 t each)
    const int h = (hg << 5) + hl;

    __shared__ float sums[8][33];

    const float* p = enc + ((size_t)b * TEq + ck * 16) * Hq + h;
    float xs[16];
#pragma unroll
    for (int i = 0; i < 16; ++i) xs[i] = p[(size_t)i * Hq];
    float tot = 0.0f;
#pragma unroll
    for (int i = 0; i < 16; ++i) tot += xs[i];
    sums[ck][hl] = tot;
    __syncthreads();

    float s = 0.0f;
    for (int c = 0; c < ck; ++c) s += sums[c][hl];   // exclusive chunk prefix

    float* q = out + ((size_t)b * TEq + ck * 16) * Hq + h;
#pragma unroll
    for (int i = 0; i < 16; ++i) {
        const float x = xs[i];
        const float r = (x * s) / (x * x);           // exact div, matches ref
        q[(size_t)i * Hq] = x - r * x;
        s += x;
    }
}

// ---------------------------------------------------------------------------
// K2: two GEMMs, C = A[2048,256] @ W[256,256], NO LDS: 64x64 tile, 256 thr,
// 4x4 thread tile. A frags broadcast through L1 (16 lanes share ty), B rows
// coalesced 256B segments; 8-k register double buffer, no barriers.
// z=0: was = enc_o@W_a (scaled by 2*log2e), z=1: uah = dec@U_a.
// Grid (4,32,2) = 256 blocks.
// ---------------------------------------------------------------------------
__global__ __launch_bounds__(256) void k_gemm2(const float* __restrict__ A0,
                                               const float* __restrict__ A1,
                                               const float* __restrict__ W0,
                                               const float* __restrict__ W1,
                                               float* __restrict__ Cw,
                                               float* __restrict__ Cu) {
    const int z = blockIdx.z;
    const float* __restrict__ A = z ? A1 : A0;
    const float* __restrict__ W = z ? W1 : W0;
    float* __restrict__ C = z ? Cu : Cw;
    const float scale = z ? 1.0f : kC2;

    const int bm = blockIdx.y * 64;
    const int bn = blockIdx.x * 64;

    const int tid = threadIdx.x;
    const int tx = tid & 15;          // n: 4 cols
    const int ty = tid >> 4;          // m: 4 rows

    const float* __restrict__ Ap = A + (size_t)(bm + (ty << 2)) * Hq;
    const float* __restrict__ Bp = W + bn + (tx << 2);

    float acc[4][4] = {};
    float4 aA[8], bA[8], aB[8], bB[8];   // double-buffered 8-k chunks

#define LOADC(ab, bb, k)                                                     \
    {                                                                        \
        _Pragma("unroll")                                                    \
        for (int r = 0; r < 4; ++r) {                                        \
            ab[r * 2 + 0] = *(const float4*)(Ap + (size_t)r * Hq + (k));     \
            ab[r * 2 + 1] = *(const float4*)(Ap + (size_t)r * Hq + (k) + 4); \
        }                                                                    \
        _Pragma("unroll")                                                    \
        for (int i = 0; i < 8; ++i)                                          \
            bb[i] = *(const float4*)(Bp + (size_t)((k) + i) * Hq);           \
    }

#define COMPC(ab, bb)                                                        \
    {                                                                        \
        _Pragma("unroll")                                                    \
        for (int q = 0; q < 2; ++q)                                          \
            _Pragma("unroll")                                                \
            for (int kk = 0; kk < 4; ++kk) {                                 \
                const float4 bv = bb[q * 4 + kk];                            \
                const float bf[4] = {bv.x, bv.y, bv.z, bv.w};                \
                _Pragma("unroll")                                            \
                for (int r = 0; r < 4; ++r) {                                \
                    const float av = (&ab[r * 2 + q].x)[kk];                 \
                    _Pragma("unroll")                                        \
                    for (int c = 0; c < 4; ++c)                              \
                        acc[r][c] = fmaf(av, bf[c], acc[r][c]);              \
                }                                                            \
            }                                                                \
    }

    LOADC(aA, bA, 0);
#pragma unroll 1
    for (int k = 0; k < Hq; k += 16) {
        if (k + 8 < Hq) LOADC(aB, bB, k + 8);
        COMPC(aA, bA);
        if (k + 16 < Hq) LOADC(aA, bA, k + 16);
        COMPC(aB, bB);
    }
#undef LOADC
#undef COMPC

#pragma unroll
    for (int r = 0; r < 4; ++r) {
        float4 o;
        o.x = acc[r][0] * scale;
        o.y = acc[r][1] * scale;
        o.z = acc[r][2] * scale;
        o.w = acc[r][3] * scale;
        *(float4*)(C + (size_t)(bm + (ty << 2) + r) * Hq + bn + (tx << 2)) = o;
    }
}

// ---------------------------------------------------------------------------
// K3: energies + softmax + context. Block = (b, 8 d's), 512 thr = 8 waves.
// Energy: wave w -> d-pair p=w&3 (d=2p,2p+1), e-half=w>>2: each was row read
// feeds TWO d's (halves was traffic). 4 sub-groups of 16 lanes per wave; each
// lane covers 16 h. tanh(z) = 1 - 2/(exp2(C2*z)+1); energy = Vsum - 2*sum(v*r).
// was pre-scaled by C2 (K2 epilogue); uah scaled at LDS load.
// Softmax: wave w -> d0+w. Context: thread-half covers 4 d's per enc_o read.
// Grid (TD/8, B) = (16,16) = 256 blocks.
// ---------------------------------------------------------------------------
__global__ __launch_bounds__(512) void k_attn(const float* __restrict__ was,
                                              const float* __restrict__ uah,
                                              const float* __restrict__ enc_o,
                                              const float* __restrict__ Va,
                                              float* __restrict__ c_out,
                                              float* __restrict__ e_out) {
    const int b = blockIdx.y;
    const int d0 = blockIdx.x << 3;

    __shared__ float uahs[8][Hq];
    __shared__ float Vs[Hq];
    __shared__ float wts[8][TEq];   // energies, then softmax weights

    const int tid = threadIdx.x;    // 0..511
    const int w = tid >> 6;         // wave 0..7
    const int lane = tid & 63;
    const int p = w & 3;            // d-pair index
    const int half = w >> 2;        // e-half

    if (tid < Hq) Vs[tid] = Va[tid];
    {
        const int hcol = tid & 255;
        for (int j = tid >> 8; j < 8; j += 2)
            uahs[j][hcol] = uah[((size_t)b * TDq + d0 + j) * Hq + hcol] * kC2;
    }
    __syncthreads();

    const int g = lane >> 4;        // sub-group 0..3
    const int ll = lane & 15;

    // Vsum (redundant per wave)
    float vs = Vs[lane] + Vs[lane + 64] + Vs[lane + 128] + Vs[lane + 192];
#pragma unroll
    for (int m = 1; m <= 32; m <<= 1) vs += __shfl_xor(vs, m);

    // preload u/v fragments for BOTH d's of the pair: h = c*64 + ll*4 + i
    float4 u0[4], u1[4], vr[4];
#pragma unroll
    for (int c = 0; c < 4; ++c) {
        u0[c] = *(const float4*)&uahs[2 * p][c * 64 + (ll << 2)];
        u1[c] = *(const float4*)&uahs[2 * p + 1][c * 64 + (ll << 2)];
        vr[c] = *(const float4*)&Vs[c * 64 + (ll << 2)];
    }

    const float* wasb = was + (size_t)b * TEq * Hq;

    for (int ei = 0; ei < 16; ++ei) {
        const int e = (half << 6) + (g << 4) + ei;
        const float* wp = wasb + (size_t)e * Hq + (ll << 2);
        float acc0 = 0.0f, acc1 = 0.0f;
#pragma unroll
        for (int c = 0; c < 4; ++c) {
            const float4 wv = *(const float4*)(wp + c * 64);
            const float wf[4] = {wv.x, wv.y, wv.z, wv.w};
            const float u0f[4] = {u0[c].x, u0[c].y, u0[c].z, u0[c].w};
            const float u1f[4] = {u1[c].x, u1[c].y, u1[c].z, u1[c].w};
            const float vf[4] = {vr[c].x, vr[c].y, vr[c].z, vr[c].w};
#pragma unroll
            for (int i = 0; i < 4; ++i) {
                const float s0 = wf[i] + u0f[i];
                const float t0 = fast_exp2(s0);
                acc0 = fmaf(vf[i], fast_rcp(t0 + 1.0f), acc0);
                const float s1 = wf[i] + u1f[i];
                const float t1 = fast_exp2(s1);
                acc1 = fmaf(vf[i], fast_rcp(t1 + 1.0f), acc1);
            }
        }
        acc0 += __shfl_xor(acc0, 1); acc1 += __shfl_xor(acc1, 1);
        acc0 += __shfl_xor(acc0, 2); acc1 += __shfl_xor(acc1, 2);
        acc0 += __shfl_xor(acc0, 4); acc1 += __shfl_xor(acc1, 4);
        acc0 += __shfl_xor(acc0, 8); acc1 += __shfl_xor(acc1, 8);
        if (ll == 0) {
            wts[2 * p][e]     = vs - 2.0f * acc0;
            wts[2 * p + 1][e] = vs - 2.0f * acc1;
        }
    }
    __syncthreads();

    // softmax: wave w handles d = d0 + w
    {
        const float v0 = wts[w][lane];
        const float v1 = wts[w][lane + 64];
        float mx = fmaxf(v0, v1);
#pragma unroll
        for (int m = 1; m <= 32; m <<= 1) mx = fmaxf(mx, __shfl_xor(mx, m));
        const float e0 = fast_exp2((v0 - mx) * kL2E);
        const float e1 = fast_exp2((v1 - mx) * kL2E);
        float sm = e0 + e1;
#pragma unroll
        for (int m = 1; m <= 32; m <<= 1) sm += __shfl_xor(sm, m);
        const float inv = fast_rcp(sm);
        const float w0 = e0 * inv;
        const float w1 = e1 * inv;
        wts[w][lane] = w0;
        wts[w][lane + 64] = w1;
        const size_t eb = ((size_t)b * TDq + d0 + w) * TEq;
        e_out[eb + lane] = w0;
        e_out[eb + lane + 64] = w1;
    }
    __syncthreads();

    // context: thread-half hh covers d = d0 + hh*4 + j; each enc_o element
    // read once per half and reused for 4 d's.
    const int h = tid & 255;
    const int db = (tid >> 8) << 2;     // 0 or 4
    float a0 = 0.0f, a1 = 0.0f, a2 = 0.0f, a3 = 0.0f;
    const float* ep = enc_o + (size_t)b * TEq * Hq + h;
#pragma unroll 4
    for (int e4 = 0; e4 < TEq; e4 += 4) {
        const float4 w0v = *(const float4*)&wts[db + 0][e4];
        const float4 w1v = *(const float4*)&wts[db + 1][e4];
        const float4 w2v = *(const float4*)&wts[db + 2][e4];
        const float4 w3v = *(const float4*)&wts[db + 3][e4];
        const float x0 = ep[(size_t)(e4 + 0) * Hq];
        const float x1 = ep[(size_t)(e4 + 1) * Hq];
        const float x2 = ep[(size_t)(e4 + 2) * Hq];
        const float x3 = ep[(size_t)(e4 + 3) * Hq];
        a0 = fmaf(w0v.x, x0, a0); a1 = fmaf(w1v.x, x0, a1);
        a2 = fmaf(w2v.x, x0, a2); a3 = fmaf(w3v.x, x0, a3);
        a0 = fmaf(w0v.y, x1, a0); a1 = fmaf(w1v.y, x1, a1);
        a2 = fmaf(w2v.y, x1, a2); a3 = fmaf(w3v.y, x1, a3);
        a0 = fmaf(w0v.z, x2, a0); a1 = fmaf(w1v.z, x2, a1);
        a2 = fmaf(w2v.z, x2, a2); a3 = fmaf(w3v.z, x2, a3);
        a0 = fmaf(w0v.w, x3, a0); a1 = fmaf(w1v.w, x3, a1);
        a2 = fmaf(w2v.w, x3, a2); a3 = fmaf(w3v.w, x3, a3);
    }
    const size_t cb = ((size_t)b * TDq + d0 + db) * Hq + h;
    c_out[cb]           = a0;
    c_out[cb + Hq]      = a1;
    c_out[cb + 2 * Hq]  = a2;
    c_out[cb + 3 * Hq]  = a3;
}

extern "C" void kernel_launch(void* const* d_in, const int* in_sizes, int n_in,
                              void* d_out, int out_size, void* d_ws, size_t ws_size,
                              hipStream_t stream) {
    const float* enc = (const float*)d_in[0];   // [16,128,256]
    const float* dec = (const float*)d_in[1];   // [16,128,256]
    const float* Wa  = (const float*)d_in[2];   // [256,256]
    const float* Ua  = (const float*)d_in[3];   // [256,256]
    const float* Va  = (const float*)d_in[4];   // [256,1]

    float* c_out = (float*)d_out;                        // [16,128,256]
    float* e_out = c_out + (size_t)Bq * TDq * Hq;        // [16,128,128]

    float* enc_o = (float*)d_ws;                         // 2 MB
    float* wasb  = enc_o + (size_t)Bq * TEq * Hq;        // 2 MB (pre-scaled by 2*log2e)
    float* uahb  = wasb + (size_t)Bq * TEq * Hq;         // 2 MB

    k_ortho<<<dim3(Hq / 32, Bq), dim3(256), 0, stream>>>(enc, enc_o);
    k_gemm2<<<dim3(Hq / 64, (Bq * TEq) / 64, 2), dim3(256), 0, stream>>>(
        enc_o, dec, Wa, Ua, wasb, uahb);
    k_attn<<<dim3(TDq / 8, Bq), dim3(512), 0, stream>>>(
        wasb, uahb, enc_o, Va, c_out, e_out);
}

// Round 5
// 102.951 us; speedup vs baseline: 1.0815x; 1.0815x over previous
//
#include <hip/hip_runtime.h>
#include <cstddef>

#define Bq 16
#define TEq 128
#define TDq 128
#define Hq 256

#define kC2  2.8853900817779268f  /* 2*log2(e) */
#define kL2E 1.4426950408889634f

static __device__ __forceinline__ float fast_rcp(float x) {
#if __has_builtin(__builtin_amdgcn_rcpf)
    return __builtin_amdgcn_rcpf(x);
#else
    return 1.0f / x;
#endif
}

static __device__ __forceinline__ float fast_exp2(float x) {
#if __has_builtin(__builtin_amdgcn_exp2f)
    return __builtin_amdgcn_exp2f(x);
#else
    return exp2f(x);
#endif
}

// ---------------------------------------------------------------------------
// K1: orthogonalize (R2 version — best measured). Exclusive cumsum over TE
// split into 8 chunks of 16 per (b,h); chunk partials via LDS.
// ---------------------------------------------------------------------------
__global__ __launch_bounds__(256) void k_ortho(const float* __restrict__ enc,
                                               float* __restrict__ out) {
    const int b = blockIdx.y;
    const int hg = blockIdx.x;            // 0..7
    const int tid = threadIdx.x;
    const int hl = tid & 31;
    const int ck = tid >> 5;              // chunk 0..7 (16 t each)
    const int h = (hg << 5) + hl;

    __shared__ float sums[8][33];

    const float* p = enc + ((size_t)b * TEq + ck * 16) * Hq + h;
    float xs[16];
#pragma unroll
    for (int i = 0; i < 16; ++i) xs[i] = p[(size_t)i * Hq];
    float tot = 0.0f;
#pragma unroll
    for (int i = 0; i < 16; ++i) tot += xs[i];
    sums[ck][hl] = tot;
    __syncthreads();

    float s = 0.0f;
    for (int c = 0; c < ck; ++c) s += sums[c][hl];   // exclusive chunk prefix

    float* q = out + ((size_t)b * TEq + ck * 16) * Hq + h;
#pragma unroll
    for (int i = 0; i < 16; ++i) {
        const float x = xs[i];
        const float r = (x * s) / (x * x);           // exact div, matches ref
        q[(size_t)i * Hq] = x - r * x;
        s += x;
    }
}

// ---------------------------------------------------------------------------
// K2: two GEMMs (R2 version — best measured). C = A[2048,256] @ W[256,256].
// z=0: was = enc_o@W_a (scaled by 2*log2e), z=1: uah = dec@U_a.
// 32x64 tile / 256 threads / 2x4 per thread / BK=16. Grid (4,64,2)=512 blocks.
// ---------------------------------------------------------------------------
__global__ __launch_bounds__(256) void k_gemm2(const float* __restrict__ A0,
                                               const float* __restrict__ A1,
                                               const float* __restrict__ W0,
                                               const float* __restrict__ W1,
                                               float* __restrict__ Cw,
                                               float* __restrict__ Cu) {
    const int z = blockIdx.z;
    const float* __restrict__ A = z ? A1 : A0;
    const float* __restrict__ W = z ? W1 : W0;
    float* __restrict__ C = z ? Cu : Cw;
    const float scale = z ? 1.0f : kC2;

    const int bm = blockIdx.y * 32;
    const int bn = blockIdx.x * 64;

    __shared__ float sA[16][33];   // [k][m] (+1 pad)
    __shared__ float sB[16][64];   // [k][n]

    const int tid = threadIdx.x;
    const int tx = tid & 15;       // n: 4 cols each
    const int ty = tid >> 4;       // m: 2 rows each
    const int arow = tid >> 3;           // 0..31
    const int akcol = (tid & 7) << 1;    // 0,2,..,14
    const int brow = tid >> 4;           // 0..15
    const int bcol = (tid & 15) << 2;    // 0..60

    float acc[2][4] = {};

    for (int k0 = 0; k0 < Hq; k0 += 16) {
        const float2 av = *(const float2*)(A + (size_t)(bm + arow) * Hq + k0 + akcol);
        const float4 bv = *(const float4*)(W + (size_t)(k0 + brow) * Hq + bn + bcol);
        __syncthreads();
        sA[akcol + 0][arow] = av.x;
        sA[akcol + 1][arow] = av.y;
        *(float4*)&sB[brow][bcol] = bv;
        __syncthreads();
#pragma unroll
        for (int k = 0; k < 16; ++k) {
            const float a0 = sA[k][ty << 1];
            const float a1 = sA[k][(ty << 1) + 1];
            const float4 b4 = *(const float4*)&sB[k][tx << 2];
            acc[0][0] = fmaf(a0, b4.x, acc[0][0]);
            acc[0][1] = fmaf(a0, b4.y, acc[0][1]);
            acc[0][2] = fmaf(a0, b4.z, acc[0][2]);
            acc[0][3] = fmaf(a0, b4.w, acc[0][3]);
            acc[1][0] = fmaf(a1, b4.x, acc[1][0]);
            acc[1][1] = fmaf(a1, b4.y, acc[1][1]);
            acc[1][2] = fmaf(a1, b4.z, acc[1][2]);
            acc[1][3] = fmaf(a1, b4.w, acc[1][3]);
        }
    }
#pragma unroll
    for (int i = 0; i < 2; ++i) {
        float4 o;
        o.x = acc[i][0] * scale;
        o.y = acc[i][1] * scale;
        o.z = acc[i][2] * scale;
        o.w = acc[i][3] * scale;
        *(float4*)(C + (size_t)(bm + (ty << 1) + i) * Hq + bn + (tx << 2)) = o;
    }
}

// ---------------------------------------------------------------------------
// K3: energies + softmax + context. Block = (b, 2 d's), 256 thr = 4 waves,
// grid (TD/2, B) = 1024 blocks -> 16 waves/CU (R2's TLP).
// NEW vs R2: wave w covers e-QUARTER w (32 e's) and computes BOTH d's per
// was-row read -> was traffic halved, 2x ILP on the exp2/rcp chains.
// 4 sub-groups of 16 lanes per wave; each lane covers 16 h.
// tanh(z) = 1 - 2/(exp2(C2*z)+1); energy = Vsum - 2*sum(v*r).
// was pre-scaled by C2 (K2 epilogue); uah scaled at LDS load.
// ---------------------------------------------------------------------------
__global__ __launch_bounds__(256) void k_attn(const float* __restrict__ was,
                                              const float* __restrict__ uah,
                                              const float* __restrict__ enc_o,
                                              const float* __restrict__ Va,
                                              float* __restrict__ c_out,
                                              float* __restrict__ e_out) {
    const int b = blockIdx.y;
    const int d0 = blockIdx.x << 1;

    __shared__ float uahs[2][Hq];
    __shared__ float Vs[Hq];
    __shared__ float wts[2][TEq];   // energies, then softmax weights

    const int tid = threadIdx.x;
    const int w = tid >> 6;         // wave 0..3 -> e-quarter
    const int lane = tid & 63;

    Vs[tid] = Va[tid];
#pragma unroll
    for (int j = 0; j < 2; ++j)
        uahs[j][tid] = uah[((size_t)b * TDq + d0 + j) * Hq + tid] * kC2;
    __syncthreads();

    const int g = lane >> 4;        // sub-group 0..3
    const int ll = lane & 15;

    // Vsum (redundant per wave)
    float vs = Vs[lane] + Vs[lane + 64] + Vs[lane + 128] + Vs[lane + 192];
#pragma unroll
    for (int m = 1; m <= 32; m <<= 1) vs += __shfl_xor(vs, m);

    // preload u/v fragments for BOTH d's: h = c*64 + ll*4 + i
    float4 u0[4], u1[4], vr[4];
#pragma unroll
    for (int c = 0; c < 4; ++c) {
        u0[c] = *(const float4*)&uahs[0][c * 64 + (ll << 2)];
        u1[c] = *(const float4*)&uahs[1][c * 64 + (ll << 2)];
        vr[c] = *(const float4*)&Vs[c * 64 + (ll << 2)];
    }

    const float* wasb = was + (size_t)b * TEq * Hq;

    for (int ei = 0; ei < 8; ++ei) {
        const int e = (w << 5) + (g << 3) + ei;   // e-quarter w, group g
        const float* wp = wasb + (size_t)e * Hq + (ll << 2);
        float acc0 = 0.0f, acc1 = 0.0f;
#pragma unroll
        for (int c = 0; c < 4; ++c) {
            const float4 wv = *(const float4*)(wp + c * 64);
            const float wf[4] = {wv.x, wv.y, wv.z, wv.w};
            const float u0f[4] = {u0[c].x, u0[c].y, u0[c].z, u0[c].w};
            const float u1f[4] = {u1[c].x, u1[c].y, u1[c].z, u1[c].w};
            const float vf[4] = {vr[c].x, vr[c].y, vr[c].z, vr[c].w};
#pragma unroll
            for (int i = 0; i < 4; ++i) {
                const float s0 = wf[i] + u0f[i];
                const float t0 = fast_exp2(s0);
                acc0 = fmaf(vf[i], fast_rcp(t0 + 1.0f), acc0);
                const float s1 = wf[i] + u1f[i];
                const float t1 = fast_exp2(s1);
                acc1 = fmaf(vf[i], fast_rcp(t1 + 1.0f), acc1);
            }
        }
        acc0 += __shfl_xor(acc0, 1); acc1 += __shfl_xor(acc1, 1);
        acc0 += __shfl_xor(acc0, 2); acc1 += __shfl_xor(acc1, 2);
        acc0 += __shfl_xor(acc0, 4); acc1 += __shfl_xor(acc1, 4);
        acc0 += __shfl_xor(acc0, 8); acc1 += __shfl_xor(acc1, 8);
        if (ll == 0) {
            wts[0][e] = vs - 2.0f * acc0;
            wts[1][e] = vs - 2.0f * acc1;
        }
    }
    __syncthreads();

    // softmax: waves 0,1 handle d = d0 + w
    if (w < 2) {
        const float v0 = wts[w][lane];
        const float v1 = wts[w][lane + 64];
        float mx = fmaxf(v0, v1);
#pragma unroll
        for (int m = 1; m <= 32; m <<= 1) mx = fmaxf(mx, __shfl_xor(mx, m));
        const float e0 = fast_exp2((v0 - mx) * kL2E);
        const float e1 = fast_exp2((v1 - mx) * kL2E);
        float sm = e0 + e1;
#pragma unroll
        for (int m = 1; m <= 32; m <<= 1) sm += __shfl_xor(sm, m);
        const float inv = fast_rcp(sm);
        const float w0 = e0 * inv;
        const float w1 = e1 * inv;
        wts[w][lane] = w0;
        wts[w][lane + 64] = w1;
        const size_t eb = ((size_t)b * TDq + d0 + w) * TEq;
        e_out[eb + lane] = w0;
        e_out[eb + lane + 64] = w1;
    }
    __syncthreads();

    // context: c[b,d0+j,h=tid] = sum_e wts[j][e] * enc_o[b,e,h]
    // wts read as float4 (b128) to cut LDS instruction count 4x.
    float a0 = 0.0f, a1 = 0.0f;
    const float* ep = enc_o + (size_t)b * TEq * Hq + tid;
#pragma unroll 4
    for (int e4 = 0; e4 < TEq; e4 += 4) {
        const float4 w0v = *(const float4*)&wts[0][e4];
        const float4 w1v = *(const float4*)&wts[1][e4];
        const float x0 = ep[(size_t)(e4 + 0) * Hq];
        const float x1 = ep[(size_t)(e4 + 1) * Hq];
        const float x2 = ep[(size_t)(e4 + 2) * Hq];
        const float x3 = ep[(size_t)(e4 + 3) * Hq];
        a0 = fmaf(w0v.x, x0, a0); a1 = fmaf(w1v.x, x0, a1);
        a0 = fmaf(w0v.y, x1, a0); a1 = fmaf(w1v.y, x1, a1);
        a0 = fmaf(w0v.z, x2, a0); a1 = fmaf(w1v.z, x2, a1);
        a0 = fmaf(w0v.w, x3, a0); a1 = fmaf(w1v.w, x3, a1);
    }
    const size_t cb = ((size_t)b * TDq + d0) * Hq + tid;
    c_out[cb] = a0;
    c_out[cb + Hq] = a1;
}

extern "C" void kernel_launch(void* const* d_in, const int* in_sizes, int n_in,
                              void* d_out, int out_size, void* d_ws, size_t ws_size,
                              hipStream_t stream) {
    const float* enc = (const float*)d_in[0];   // [16,128,256]
    const float* dec = (const float*)d_in[1];   // [16,128,256]
    const float* Wa  = (const float*)d_in[2];   // [256,256]
    const float* Ua  = (const float*)d_in[3];   // [256,256]
    const float* Va  = (const float*)d_in[4];   // [256,1]

    float* c_out = (float*)d_out;                        // [16,128,256]
    float* e_out = c_out + (size_t)Bq * TDq * Hq;        // [16,128,128]

    float* enc_o = (float*)d_ws;                         // 2 MB
    float* wasb  = enc_o + (size_t)Bq * TEq * Hq;        // 2 MB (pre-scaled by 2*log2e)
    float* uahb  = wasb + (size_t)Bq * TEq * Hq;         // 2 MB

    k_ortho<<<dim3(Hq / 32, Bq), dim3(256), 0, stream>>>(enc, enc_o);
    k_gemm2<<<dim3(Hq / 64, (Bq * TEq) / 32, 2), dim3(256), 0, stream>>>(
        enc_o, dec, Wa, Ua, wasb, uahb);
    k_attn<<<dim3(TDq / 2, Bq), dim3(256), 0, stream>>>(
        wasb, uahb, enc_o, Va, c_out, e_out);
}